// Round 11
// baseline (565.125 us; speedup 1.0000x reference)
//
#include <hip/hip_runtime.h>
#include <hip/hip_bf16.h>

#define NBAND 7
#define BBATCH 16
#define TSEQ 512
#define DMODEL 128
#define MBAND (BBATCH * TSEQ)               // 8192 rows per band
#define BANDE ((size_t)MBAND * DMODEL)      // 1,048,576 elements per band

typedef __attribute__((ext_vector_type(8))) short short8;
typedef __attribute__((ext_vector_type(4))) float f32x4;
typedef unsigned int u32;
typedef unsigned short u16;

__device__ __forceinline__ u16 f2bf(float x) {
  unsigned u = __float_as_uint(x);
  unsigned r = u + 0x7FFF + ((u >> 16) & 1);   // RNE
  return (u16)(r >> 16);
}
__device__ __forceinline__ u32 pack2(float a, float b) {
  return (u32)f2bf(a) | ((u32)f2bf(b) << 16);
}
__device__ __forceinline__ float b2f(u16 h) {
  return __uint_as_float((u32)h << 16);
}

// ---------------------------------------------------------------------------
// MFMA part, 64m x 128n tile: acc[2][4] += A(64xK bf16) @ W(KxN fp32) at
// (m0, n0). 256 thr = 4 waves 2x2 (wave = 32m x 64n), K-step 32.
// As[64][40] bf16 [m][k]; Bs[128][40] bf16 [n][k] transposed at staging.
// ---------------------------------------------------------------------------
__device__ __forceinline__ void mfma_part_h(const u16* __restrict__ A,
                                            const float* __restrict__ W,
                                            int K, int N, int m0, int n0, int tid,
                                            u16 (*As)[40], u16 (*Bs)[40],
                                            f32x4 acc[2][4]) {
  const int lane = tid & 63;
  const int wv = tid >> 6;
  const int wr = wv >> 1, wc = wv & 1;
  const int lr = lane & 15, k8 = lane >> 4;

  for (int k0 = 0; k0 < K; k0 += 32) {
    {   // stage A: 64 rows x 32 k bf16; one contiguous short8 per thread
      int row = tid >> 2, kq = (tid & 3) << 3;
      *(short8*)&As[row][kq] =
          *(const short8*)&A[(size_t)(m0 + row) * K + k0 + kq];
    }
    #pragma unroll
    for (int it = 0; it < 4; ++it) {   // stage B: 32 k x 128 n (fp32 W -> bf16 T)
      int idx = tid + it * 256;        // 1024 float4 units
      int k = idx >> 5, nq = (idx & 31) << 2;
      const float4 v = *(const float4*)&W[(size_t)(k0 + k) * N + n0 + nq];
      Bs[nq + 0][k] = f2bf(v.x); Bs[nq + 1][k] = f2bf(v.y);
      Bs[nq + 2][k] = f2bf(v.z); Bs[nq + 3][k] = f2bf(v.w);
    }
    __syncthreads();
    short8 a0 = *(const short8*)&As[wr * 32 + lr][k8 * 8];
    short8 a1 = *(const short8*)&As[wr * 32 + 16 + lr][k8 * 8];
    #pragma unroll
    for (int j = 0; j < 4; ++j) {
      short8 b = *(const short8*)&Bs[wc * 64 + j * 16 + lr][k8 * 8];
      acc[0][j] = __builtin_amdgcn_mfma_f32_16x16x32_bf16(a0, b, acc[0][j], 0, 0, 0);
      acc[1][j] = __builtin_amdgcn_mfma_f32_16x16x32_bf16(a1, b, acc[1][j], 0, 0, 0);
    }
    __syncthreads();
  }
}

// ---------------------------------------------------------------------------
// Batched GEMM over blockIdx.z (bf16 activations, fp32 weights), 64x128 tile.
// ---------------------------------------------------------------------------
struct PArgs {
  const u16 *A, *A2;
  const float *W, *W2, *bias;
  const float* residF;          // op3 (fp32 residual = original input)
  const u16 *residH, *extraH;   // op4/5 (bf16 residual/extra)
  float* OF;                    // op4 output (fp32 final)
  u16* OH;                      // other outputs (bf16)
  size_t Aoff[8], Woff[8], boff[8], A2off[8], W2off[8], roff[8], eoff[8], Ooff[8];
  int K, N, op;   // 0 store 1 gelu 2 sigmoid 3 residF+ 4 residH+sig(v)*extraH->f32 5 residH+extraH*v
};

__global__ __launch_bounds__(256) void gemm_b(PArgs p) {
  __shared__ __align__(16) u16 As[64][40];
  __shared__ __align__(16) u16 Bs[128][40];
  const int z = blockIdx.z;
  const int m0 = blockIdx.x * 64, n0 = blockIdx.y * 128;
  const int tid = threadIdx.x;
  f32x4 acc[2][4] = {};

  mfma_part_h(p.A + p.Aoff[z], p.W + p.Woff[z], p.K, p.N, m0, n0, tid, As, Bs, acc);
  if (p.A2)
    mfma_part_h(p.A2 + p.A2off[z], p.W2 + p.W2off[z], p.K, p.N, m0, n0, tid, As, Bs, acc);

  const float* bias = p.bias ? p.bias + p.boff[z] : nullptr;
  const int lane = tid & 63;
  const int wv = tid >> 6;
  const int wr = wv >> 1, wc = wv & 1;
  const int lr = lane & 15, lg = lane >> 4;

  #pragma unroll
  for (int i = 0; i < 2; ++i) {
    #pragma unroll
    for (int j = 0; j < 4; ++j) {
      #pragma unroll
      for (int r = 0; r < 4; ++r) {
        int m = m0 + wr * 32 + i * 16 + lg * 4 + r;
        int n = n0 + wc * 64 + j * 16 + lr;
        float v = acc[i][j][r];
        if (bias) v += bias[n];
        size_t idx = (size_t)m * p.N + n;
        switch (p.op) {
          case 0: p.OH[p.Ooff[z] + idx] = f2bf(v); break;
          case 1: p.OH[p.Ooff[z] + idx] =
                    f2bf(0.5f * v * (1.f + erff(v * 0.70710678118654752f))); break;
          case 2: p.OH[p.Ooff[z] + idx] = f2bf(1.f / (1.f + __expf(-v))); break;
          case 3: p.OH[p.Ooff[z] + idx] =
                    f2bf(p.residF[p.roff[z] + idx] + v); break;
          case 4: {
            float gate = 1.f / (1.f + __expf(-v));
            p.OF[p.Ooff[z] + idx] = b2f(p.residH[p.roff[z] + idx]) +
                                    gate * b2f(p.extraH[p.eoff[z] + idx]);
          } break;
          case 5: {
            float gm = p.extraH ? b2f(p.extraH[p.eoff[z] + idx]) : 1.f;
            p.OH[p.Ooff[z] + idx] = f2bf(b2f(p.residH[p.roff[z] + idx]) + gm * v);
          } break;
        }
      }
    }
  }
}

// 6-part bridge: O = bf16( (sum_s y[bl_s] @ br_w[s]) / 6 + bbias ), 64x128 tile
__global__ __launch_bounds__(256) void bridge_kernel(const u16* __restrict__ yb,
                                                     const float* __restrict__ br_w,
                                                     const float* __restrict__ bbias,
                                                     u16* __restrict__ O) {
  __shared__ __align__(16) u16 As[64][40];
  __shared__ __align__(16) u16 Bs[128][40];
  const int m0 = blockIdx.x * 64;
  const int tid = threadIdx.x;
  f32x4 acc[2][4] = {};
  const int bl[6] = {0, 1, 2, 4, 5, 6};
  for (int s = 0; s < 6; ++s)
    mfma_part_h(yb + (size_t)bl[s] * BANDE, br_w + s * 16384, 128, 128, m0, 0, tid, As, Bs, acc);

  const int lane = tid & 63;
  const int wv = tid >> 6;
  const int wr = wv >> 1, wc = wv & 1;
  const int lr = lane & 15, lg = lane >> 4;
  #pragma unroll
  for (int i = 0; i < 2; ++i)
    #pragma unroll
    for (int j = 0; j < 4; ++j)
      #pragma unroll
      for (int r = 0; r < 4; ++r) {
        int m = m0 + wr * 32 + i * 16 + lg * 4 + r;
        int n = wc * 64 + j * 16 + lr;
        O[(size_t)m * 128 + n] = f2bf(acc[i][j][r] * (1.f / 6.f) + bbias[n]);
      }
}

// ---------------------------------------------------------------------------
// MFMA flash attention, causal, bf16 (unchanged from round 9).
// ---------------------------------------------------------------------------
__global__ __launch_bounds__(256) void attn_kernel(const u16* __restrict__ q,
                                                   const u16* __restrict__ k,
                                                   const u16* __restrict__ v,
                                                   u16* __restrict__ o) {
  const int band = blockIdx.x >> 8;
  const int rest = blockIdx.x & 255;
  const int qt = rest & 7;
  const int bh = rest >> 3;
  const int h  = bh & 1;
  const int b  = bh >> 1;
  const size_t rowbase = ((size_t)band * BBATCH + b) * TSEQ;

  const int tid  = threadIdx.x;
  const int w    = tid >> 6;
  const int lane = tid & 63;
  const int lr   = lane & 15;
  const int lg   = lane >> 4;

  __shared__ __align__(16) u16 Qs[64][72];
  __shared__ __align__(16) u16 Ks[64][72];
  __shared__ __align__(16) u16 Vs[64][72];
  __shared__ __align__(16) u16 Ps[4][16][72];

  #pragma unroll
  for (int it = 0; it < 2; ++it) {
    int idx = tid + it * 256;
    int r = idx >> 3, c8 = (idx & 7) << 3;
    *(short8*)&Qs[r][c8] =
        *(const short8*)&q[(rowbase + qt * 64 + r) * DMODEL + h * 64 + c8];
  }

  f32x4 oacc[4] = {};
  float m[4], l[4];
  #pragma unroll
  for (int r = 0; r < 4; ++r) { m[r] = -1e30f; l[r] = 0.f; }

  for (int kt = 0; kt <= qt; ++kt) {
    __syncthreads();
    #pragma unroll
    for (int it = 0; it < 2; ++it) {
      int idx = tid + it * 256;
      int r = idx >> 3, c8 = (idx & 7) << 3;
      *(short8*)&Ks[r][c8] =
          *(const short8*)&k[(rowbase + kt * 64 + r) * DMODEL + h * 64 + c8];
    }
    #pragma unroll
    for (int it = 0; it < 2; ++it) {
      int idx = tid + it * 256;
      int kp = idx >> 4, d0 = (idx & 15) << 2;
      size_t g0 = (rowbase + kt * 64 + 2 * kp) * DMODEL + h * 64 + d0;
      u32 a0 = *(const u32*)&v[g0];
      u32 a1 = *(const u32*)&v[g0 + 2];
      u32 b0 = *(const u32*)&v[g0 + DMODEL];
      u32 b1 = *(const u32*)&v[g0 + DMODEL + 2];
      *(u32*)&Vs[d0 + 0][2 * kp] = (a0 & 0xFFFFu) | (b0 << 16);
      *(u32*)&Vs[d0 + 1][2 * kp] = (a0 >> 16) | (b0 & 0xFFFF0000u);
      *(u32*)&Vs[d0 + 2][2 * kp] = (a1 & 0xFFFFu) | (b1 << 16);
      *(u32*)&Vs[d0 + 3][2 * kp] = (a1 >> 16) | (b1 & 0xFFFF0000u);
    }
    __syncthreads();

    f32x4 s[4] = {};
    #pragma unroll
    for (int c = 0; c < 2; ++c) {
      short8 a = *(const short8*)&Qs[w * 16 + lr][c * 32 + lg * 8];
      #pragma unroll
      for (int j = 0; j < 4; ++j) {
        short8 bb = *(const short8*)&Ks[j * 16 + lr][c * 32 + lg * 8];
        s[j] = __builtin_amdgcn_mfma_f32_16x16x32_bf16(a, bb, s[j], 0, 0, 0);
      }
    }
    #pragma unroll
    for (int j = 0; j < 4; ++j)
      #pragma unroll
      for (int r = 0; r < 4; ++r)
        s[j][r] *= 0.125f;

    if (kt == qt) {
      #pragma unroll
      for (int j = 0; j < 4; ++j)
        #pragma unroll
        for (int r = 0; r < 4; ++r) {
          int row = w * 16 + lg * 4 + r;
          int col = j * 16 + lr;
          if (col > row) s[j][r] = -1e30f;
        }
    }

    float mx[4], al[4];
    #pragma unroll
    for (int r = 0; r < 4; ++r)
      mx[r] = fmaxf(fmaxf(s[0][r], s[1][r]), fmaxf(s[2][r], s[3][r]));
    #pragma unroll
    for (int off = 1; off <= 8; off <<= 1)
      #pragma unroll
      for (int r = 0; r < 4; ++r)
        mx[r] = fmaxf(mx[r], __shfl_xor(mx[r], off));
    #pragma unroll
    for (int r = 0; r < 4; ++r) {
      float mn = fmaxf(m[r], mx[r]);
      al[r] = __expf(m[r] - mn);
      m[r] = mn;
    }
    float rs[4] = {0.f, 0.f, 0.f, 0.f};
    #pragma unroll
    for (int j = 0; j < 4; ++j)
      #pragma unroll
      for (int r = 0; r < 4; ++r) {
        float pe = __expf(s[j][r] - m[r]);
        s[j][r] = pe;
        rs[r] += pe;
      }
    #pragma unroll
    for (int off = 1; off <= 8; off <<= 1)
      #pragma unroll
      for (int r = 0; r < 4; ++r)
        rs[r] += __shfl_xor(rs[r], off);
    #pragma unroll
    for (int r = 0; r < 4; ++r) l[r] = l[r] * al[r] + rs[r];

    #pragma unroll
    for (int j = 0; j < 4; ++j)
      #pragma unroll
      for (int r = 0; r < 4; ++r)
        oacc[j][r] *= al[r];

    #pragma unroll
    for (int j = 0; j < 4; ++j)
      #pragma unroll
      for (int r = 0; r < 4; ++r)
        Ps[w][lg * 4 + r][j * 16 + lr] = f2bf(s[j][r]);

    #pragma unroll
    for (int c = 0; c < 2; ++c) {
      short8 a = *(const short8*)&Ps[w][lr][c * 32 + lg * 8];
      #pragma unroll
      for (int j = 0; j < 4; ++j) {
        short8 bb = *(const short8*)&Vs[j * 16 + lr][c * 32 + lg * 8];
        oacc[j] = __builtin_amdgcn_mfma_f32_16x16x32_bf16(a, bb, oacc[j], 0, 0, 0);
      }
    }
  }

  float inv[4];
  #pragma unroll
  for (int r = 0; r < 4; ++r) inv[r] = 1.f / l[r];
  #pragma unroll
  for (int j = 0; j < 4; ++j)
    #pragma unroll
    for (int r = 0; r < 4; ++r) {
      size_t row = rowbase + qt * 64 + w * 16 + lg * 4 + r;
      o[row * DMODEL + h * 64 + j * 16 + lr] = f2bf(oacc[j][r] * inv[r]);
    }
}

// ---------------------------------------------------------------------------
struct LNA {
  const u16* x;
  u16* xn;
  const float* ls[7];
  const float* lb[7];
};

__global__ __launch_bounds__(256) void ln_kernel(LNA p) {
  const int tid = threadIdx.x;
  const int rr = tid >> 6, lane = tid & 63;
  const size_t row = (size_t)blockIdx.x * 4 + rr;
  u32 wv = *(const u32*)&p.x[row * DMODEL + 2 * lane];
  float a = b2f((u16)wv), b = b2f((u16)(wv >> 16));
  float s = a + b;
  #pragma unroll
  for (int off = 32; off; off >>= 1) s += __shfl_xor(s, off);
  float mean = s * (1.f / 128.f);
  float da = a - mean, db = b - mean;
  float vs = da * da + db * db;
  #pragma unroll
  for (int off = 32; off; off >>= 1) vs += __shfl_xor(vs, off);
  float rstd = rsqrtf(vs * (1.f / 128.f) + 1e-5f);
  int band = (int)(row >> 13);
  const float* ls = p.ls[band];
  const float* lb = p.lb[band];
  *(u32*)&p.xn[row * DMODEL + 2 * lane] =
      pack2(da * rstd * ls[2 * lane] + lb[2 * lane],
            db * rstd * ls[2 * lane + 1] + lb[2 * lane + 1]);
}

__global__ void bias6_kernel(const float* __restrict__ br_b, float* __restrict__ out) {
  int d = threadIdx.x;
  float s = 0.f;
  #pragma unroll
  for (int j = 0; j < 6; ++j) s += br_b[j * 128 + d];
  out[d] = s * (1.f / 6.f);
}

__global__ __launch_bounds__(256) void cvt_kernel(const float* __restrict__ in,
                                                  u16* __restrict__ out) {
  size_t i = ((size_t)blockIdx.x * 256 + threadIdx.x) * 8;
  float4 a = *(const float4*)&in[i];
  float4 b = *(const float4*)&in[i + 4];
  uint4 st = {pack2(a.x, a.y), pack2(a.z, a.w), pack2(b.x, b.y), pack2(b.z, b.w)};
  *(uint4*)&out[i] = st;
}

// ---------------------------------------------------------------------------
extern "C" void kernel_launch(void* const* d_in, const int* in_sizes, int n_in,
                              void* d_out, int out_size, void* d_ws, size_t ws_size,
                              hipStream_t stream) {
  bool dict = (in_sizes[2] != 896);
  const float* bands = (const float*)d_in[0];
  const float* Wq = (const float*)d_in[1];
  const float *Wk, *Wv, *Wo, *bq, *bk, *bv, *bo;
  if (dict) {
    Wk = (const float*)d_in[2]; Wv = (const float*)d_in[3]; Wo = (const float*)d_in[4];
    bq = (const float*)d_in[5]; bk = (const float*)d_in[6];
    bv = (const float*)d_in[7]; bo = (const float*)d_in[8];
  } else {
    bq = (const float*)d_in[2]; Wk = (const float*)d_in[3]; bk = (const float*)d_in[4];
    Wv = (const float*)d_in[5]; bv = (const float*)d_in[6];
    Wo = (const float*)d_in[7]; bo = (const float*)d_in[8];
  }
  const float* g_ls = (const float*)d_in[9];
  const float* g_lb = (const float*)d_in[10];
  const float* g_w1 = (const float*)d_in[11];
  const float* g_b1 = (const float*)d_in[12];
  const float* g_w2 = (const float*)d_in[13];
  const float* g_b2 = (const float*)d_in[14];
  const float* g_wg = (const float*)d_in[15];
  const float* g_bg = (const float*)d_in[16];
  const float* h_ls = (const float*)d_in[17];
  const float* h_lb = (const float*)d_in[18];
  const float* h_w1 = (const float*)d_in[19];
  const float* h_b1 = (const float*)d_in[20];
  const float* h_w2 = (const float*)d_in[21];
  const float* h_b2 = (const float*)d_in[22];
  const float* r_ls = (const float*)d_in[23];
  const float* r_lb = (const float*)d_in[24];
  const float* r_w1 = (const float*)d_in[25];
  const float* r_b1 = (const float*)d_in[26];
  const float* r_w2 = (const float*)d_in[27];
  const float* r_b2 = (const float*)d_in[28];
  const float* wp_w = (const float*)d_in[29];
  const float* wp_b = (const float*)d_in[30];
  const float* wg_w = (const float*)d_in[31];
  const float* wg_b = (const float*)d_in[32];
  const float* br_w = (const float*)d_in[33];
  const float* br_b = (const float*)d_in[34];
  const float* bg_w = (const float*)d_in[35];
  const float* bg_b = (const float*)d_in[36];
  float* out = (float*)d_out;

  const float* lsP[7] = {g_ls, g_ls + 128, g_ls + 256, h_ls, h_ls + 128, r_ls, r_ls + 128};
  const float* lbP[7] = {g_lb, g_lb + 128, g_lb + 256, h_lb, h_lb + 128, r_lb, r_lb + 128};
  const float* w1p[7] = {g_w1, g_w1 + 32768, g_w1 + 65536,
                         h_w1, h_w1 + 49152, r_w1, r_w1 + 65536};
  const float* b1p[7] = {g_b1, g_b1 + 256, g_b1 + 512,
                         h_b1, h_b1 + 384, r_b1, r_b1 + 512};
  const float* w2p[7] = {g_w2, g_w2 + 32768, g_w2 + 65536,
                         h_w2, h_w2 + 49152, r_w2, r_w2 + 65536};
  const float* b2p[7] = {g_b2, g_b2 + 128, g_b2 + 256,
                         h_b2, h_b2 + 128, r_b2, r_b2 + 128};

  auto LP = [&](PArgs& p, int Z) {
    dim3 grid(MBAND / 64, p.N / 128, Z);
    gemm_b<<<grid, dim3(256), 0, stream>>>(p);
  };

  // ---- bf16 workspace layout (~97 MB), identical to round 9 ----
  const size_t HIDSZ = (size_t)MBAND * 2304;
  u16* H = (u16*)d_ws;
  u16* hidh   = H;                       // HIDSZ (overlays bandsH, later info/bridge)
  u16* bandsH = hidh;                    // 7 BANDE, dead after QKV
  u16* qh = H + HIDSZ;
  u16* kh = qh + 7 * BANDE;
  u16* vh = kh + 7 * BANDE;
  u16* oh = vh + 7 * BANDE;
  float* bbias = (float*)(oh + 7 * BANDE);
  u16* xh = qh;
  u16* xnh = kh;
  u16* gateh = vh;
  u16* yh = oh;
  u16* infoh = hidh;
  u16* bridgeh = hidh + 6 * BANDE;

  // 0. bands -> bf16
  cvt_kernel<<<dim3((unsigned)(7 * BANDE / (8 * 256))), dim3(256), 0, stream>>>(bands, bandsH);

  // 1-3. Q/K/V projections, Z=7 each
  const float* Wqkv[3] = {Wq, Wk, Wv};
  const float* bqkv[3] = {bq, bk, bv};
  u16* oqkv[3] = {qh, kh, vh};
  for (int w = 0; w < 3; ++w) {
    PArgs p{};
    p.A = bandsH; p.W = Wqkv[w]; p.bias = bqkv[w]; p.OH = oqkv[w];
    for (int z = 0; z < 7; ++z) {
      p.Aoff[z] = z * BANDE; p.Woff[z] = (size_t)z * 16384;
      p.boff[z] = (size_t)z * 128; p.Ooff[z] = z * BANDE;
    }
    p.K = 128; p.N = 128; p.op = 0;
    LP(p, 7);
  }

  // 4. attention
  attn_kernel<<<dim3(NBAND * 256), dim3(256), 0, stream>>>(qh, kh, vh, oh);

  // 5. x = bands + o @ Wo + bo   (resid fp32 input, out bf16)
  {
    PArgs p{};
    p.A = oh; p.W = Wo; p.bias = bo; p.residF = bands; p.OH = xh;
    for (int z = 0; z < 7; ++z) {
      p.Aoff[z] = z * BANDE; p.Woff[z] = (size_t)z * 16384;
      p.boff[z] = (size_t)z * 128; p.roff[z] = z * BANDE; p.Ooff[z] = z * BANDE;
    }
    p.K = 128; p.N = 128; p.op = 3;
    LP(p, 7);
  }

  // 6. LN
  {
    LNA p{};
    p.x = xh; p.xn = xnh;
    for (int n = 0; n < 7; ++n) { p.ls[n] = lsP[n]; p.lb[n] = lbP[n]; }
    ln_kernel<<<dim3(NBAND * MBAND / 4), dim3(256), 0, stream>>>(p);
  }

  // 7. geo gates, Z=3
  {
    PArgs p{};
    p.A = xh; p.W = g_wg; p.bias = g_bg; p.OH = gateh;
    for (int z = 0; z < 3; ++z) {
      p.Aoff[z] = z * BANDE; p.Woff[z] = (size_t)z * 16384;
      p.boff[z] = (size_t)z * 128; p.Ooff[z] = z * BANDE;
    }
    p.K = 128; p.N = 128; p.op = 2;
    LP(p, 3);
  }

  // 8-13. MLP per group: geo(3,256) hyb(2,384) rea(2,512)
  const int gcnt[3] = {3, 2, 2};
  const int gbase[3] = {0, 3, 5};
  const int gN1[3] = {256, 384, 512};
  for (int grp = 0; grp < 3; ++grp) {
    int cnt = gcnt[grp], base = gbase[grp], N1 = gN1[grp];
    size_t hstride = (size_t)MBAND * N1;
    {  // hidden = gelu(xn @ w1 + b1)
      PArgs p{};
      p.A = xnh; p.W = w1p[base]; p.bias = b1p[base]; p.OH = hidh;
      for (int z = 0; z < cnt; ++z) {
        p.Aoff[z] = (size_t)(base + z) * BANDE;
        p.Woff[z] = (size_t)(w1p[base + z] - w1p[base]);
        p.boff[z] = (size_t)(b1p[base + z] - b1p[base]);
        p.Ooff[z] = z * hstride;
      }
      p.K = 128; p.N = N1; p.op = 1;
      LP(p, cnt);
    }
    {  // y = x + [gate]*(hid @ w2 + b2)
      PArgs p{};
      p.A = hidh; p.W = w2p[base]; p.bias = b2p[base];
      p.residH = xh; p.OH = yh;
      if (grp == 0) p.extraH = gateh;
      for (int z = 0; z < cnt; ++z) {
        p.Aoff[z] = z * hstride;
        p.Woff[z] = (size_t)(w2p[base + z] - w2p[base]);
        p.boff[z] = (size_t)(b2p[base + z] - b2p[base]);
        p.roff[z] = (size_t)(base + z) * BANDE;
        p.eoff[z] = z * BANDE;
        p.Ooff[z] = (size_t)(base + z) * BANDE;
      }
      p.K = N1; p.N = 128; p.op = 5;
      LP(p, cnt);
    }
  }

  // 14. info, Z=6
  {
    PArgs p{};
    p.A = yh; p.W = wp_w; p.bias = wp_b; p.OH = infoh;
    for (int z = 0; z < 6; ++z) {
      int t = (z < 3) ? z : z + 1;
      int src = 6 - t;
      int i = (t < 3) ? t : 6 - t;
      p.Aoff[z] = (size_t)src * BANDE; p.Woff[z] = (size_t)i * 16384;
      p.boff[z] = (size_t)i * 128; p.Ooff[z] = (size_t)z * BANDE;
    }
    p.K = 128; p.N = 128; p.op = 0;
    LP(p, 6);
  }

  // 15. final gates (2-part K), fp32 out
  {
    PArgs p{};
    p.A = yh; p.W = wg_w; p.A2 = infoh; p.W2 = wg_w;
    p.bias = wg_b; p.residH = yh; p.extraH = infoh; p.OF = out;
    for (int z = 0; z < 6; ++z) {
      int t = (z < 3) ? z : z + 1;
      int i = (t < 3) ? t : 6 - t;
      p.Aoff[z] = (size_t)t * BANDE;  p.Woff[z] = (size_t)i * 32768;
      p.A2off[z] = (size_t)z * BANDE; p.W2off[z] = (size_t)i * 32768 + 16384;
      p.boff[z] = (size_t)i * 128;
      p.roff[z] = (size_t)t * BANDE;  p.eoff[z] = (size_t)z * BANDE;
      p.Ooff[z] = (size_t)t * BANDE;
    }
    p.K = 128; p.N = 128; p.op = 4;
    LP(p, 6);
  }

  // 16-17. bridge
  bias6_kernel<<<dim3(1), dim3(128), 0, stream>>>(br_b, bbias);
  bridge_kernel<<<dim3(MBAND / 64), dim3(256), 0, stream>>>(yh, br_w, bbias, bridgeh);

  // 18. band-3 final (2-part), fp32 out
  {
    PArgs p{};
    p.A = yh; p.W = bg_w; p.A2 = bridgeh; p.W2 = bg_w;
    p.bias = bg_b; p.residH = yh; p.extraH = bridgeh; p.OF = out;
    p.Aoff[0] = 3 * BANDE; p.Woff[0] = 0;
    p.A2off[0] = 0; p.W2off[0] = 16384;
    p.boff[0] = 0; p.roff[0] = 3 * BANDE; p.eoff[0] = 0; p.Ooff[0] = 3 * BANDE;
    p.K = 128; p.N = 128; p.op = 4;
    LP(p, 1);
  }
}

// Round 12
// 309.676 us; speedup vs baseline: 1.8249x; 1.8249x over previous
//
#include <hip/hip_runtime.h>
#include <hip/hip_bf16.h>

#define NBAND 7
#define BBATCH 16
#define TSEQ 512
#define DMODEL 128
#define MBAND (BBATCH * TSEQ)               // 8192 rows per band
#define BANDE ((size_t)MBAND * DMODEL)      // 1,048,576 elements per band

typedef __attribute__((ext_vector_type(8))) short short8;
typedef __attribute__((ext_vector_type(4))) float f32x4;
typedef unsigned int u32;
typedef unsigned short u16;

__device__ __forceinline__ u16 f2bf(float x) {
  unsigned u = __float_as_uint(x);
  unsigned r = u + 0x7FFF + ((u >> 16) & 1);   // RNE
  return (u16)(r >> 16);
}
__device__ __forceinline__ u32 pack2(float a, float b) {
  return (u32)f2bf(a) | ((u32)f2bf(b) << 16);
}
__device__ __forceinline__ float b2f(u16 h) {
  return __uint_as_float((u32)h << 16);
}

// ===========================================================================
// Weight transpose+convert: src fp32 [K][N] -> dst bf16 [N][K]. Runs once.
// grid (64, 1, nslices); 64x64 tiles with bounds guard.
// ===========================================================================
struct TSlice { const float* src; u16* dst; int K, N; };
struct TArgs { TSlice s[62]; };

__global__ __launch_bounds__(256) void wtrans_kernel(TArgs a) {
  TSlice sl = a.s[blockIdx.z];
  const int tk = (blockIdx.x & 7) * 64, tn = (blockIdx.x >> 3) * 64;
  if (tk >= sl.K || tn >= sl.N) return;
  __shared__ __align__(16) u16 T[64][72];
  const int tid = threadIdx.x;
  #pragma unroll
  for (int it = 0; it < 4; ++it) {
    int idx = tid + it * 256;                 // 1024 float4 units
    int k = idx >> 4, nq = (idx & 15) << 2;
    float4 v = *(const float4*)&sl.src[(size_t)(tk + k) * sl.N + tn + nq];
    T[nq + 0][k] = f2bf(v.x); T[nq + 1][k] = f2bf(v.y);
    T[nq + 2][k] = f2bf(v.z); T[nq + 3][k] = f2bf(v.w);
  }
  __syncthreads();
  #pragma unroll
  for (int it = 0; it < 2; ++it) {
    int idx = tid + it * 256;                 // 512 short8 units
    int n = idx >> 3, kq = (idx & 7) << 3;
    *(short8*)&sl.dst[(size_t)(tn + n) * sl.K + tk + kq] = *(const short8*)&T[n][kq];
  }
}

// ---------------------------------------------------------------------------
// MFMA part (round-9 engine, bf16 both operands): acc[2][2] +=
// A(64xK bf16 [M][K]) @ WT(bf16 [N][K]) for 64x64 tile at (m0, n0).
// 256 thr = 4 waves 2x2 (wave = 32x32), K-step 32. Both stages are pure
// contiguous short8 copies -> coalesced global loads, vector LDS writes.
// ---------------------------------------------------------------------------
__device__ __forceinline__ void mfma_part_h(const u16* __restrict__ A,
                                            const u16* __restrict__ WT,
                                            int K, int m0, int n0, int tid,
                                            u16 (*As)[40], u16 (*Bs)[40],
                                            f32x4 acc[2][2]) {
  const int lane = tid & 63;
  const int wv = tid >> 6;
  const int wr = wv >> 1, wc = wv & 1;
  const int lr = lane & 15, k8 = lane >> 4;
  const int row = tid >> 2, kq = (tid & 3) << 3;

  for (int k0 = 0; k0 < K; k0 += 32) {
    *(short8*)&As[row][kq] = *(const short8*)&A[(size_t)(m0 + row) * K + k0 + kq];
    *(short8*)&Bs[row][kq] = *(const short8*)&WT[(size_t)(n0 + row) * K + k0 + kq];
    __syncthreads();
    short8 a0 = *(const short8*)&As[wr * 32 + lr][k8 * 8];
    short8 a1 = *(const short8*)&As[wr * 32 + 16 + lr][k8 * 8];
    short8 b0 = *(const short8*)&Bs[wc * 32 + lr][k8 * 8];
    short8 b1 = *(const short8*)&Bs[wc * 32 + 16 + lr][k8 * 8];
    acc[0][0] = __builtin_amdgcn_mfma_f32_16x16x32_bf16(a0, b0, acc[0][0], 0, 0, 0);
    acc[0][1] = __builtin_amdgcn_mfma_f32_16x16x32_bf16(a0, b1, acc[0][1], 0, 0, 0);
    acc[1][0] = __builtin_amdgcn_mfma_f32_16x16x32_bf16(a1, b0, acc[1][0], 0, 0, 0);
    acc[1][1] = __builtin_amdgcn_mfma_f32_16x16x32_bf16(a1, b1, acc[1][1], 0, 0, 0);
    __syncthreads();
  }
}

// ---------------------------------------------------------------------------
// Batched GEMM over blockIdx.z (bf16 activations, bf16 pre-transposed W).
// ---------------------------------------------------------------------------
struct PArgs {
  const u16 *A, *A2;
  const u16 *WT, *WT2;          // bf16 [N][K]
  const float* bias;
  const float* residF;          // op3 (fp32 residual = original input)
  const u16 *residH, *extraH;   // op4/5 (bf16 residual/extra)
  float* OF;                    // op4 output (fp32 final)
  u16* OH;                      // other outputs (bf16)
  size_t Aoff[8], Woff[8], boff[8], A2off[8], W2off[8], roff[8], eoff[8], Ooff[8];
  int K, N, op;   // 0 store 1 gelu 2 sigmoid 3 residF+ 4 residH+sig(v)*extraH->f32 5 residH+extraH*v
};

__global__ __launch_bounds__(256) void gemm_b(PArgs p) {
  __shared__ __align__(16) u16 As[64][40];
  __shared__ __align__(16) u16 Bs[64][40];
  const int z = blockIdx.z;
  const int m0 = blockIdx.x * 64, n0 = blockIdx.y * 64;
  const int tid = threadIdx.x;
  f32x4 acc[2][2] = {};

  mfma_part_h(p.A + p.Aoff[z], p.WT + p.Woff[z], p.K, m0, n0, tid, As, Bs, acc);
  if (p.A2)
    mfma_part_h(p.A2 + p.A2off[z], p.WT2 + p.W2off[z], p.K, m0, n0, tid, As, Bs, acc);

  const float* bias = p.bias ? p.bias + p.boff[z] : nullptr;
  const int lane = tid & 63;
  const int wv = tid >> 6;
  const int wr = wv >> 1, wc = wv & 1;
  const int lr = lane & 15, lg = lane >> 4;

  #pragma unroll
  for (int i = 0; i < 2; ++i) {
    #pragma unroll
    for (int j = 0; j < 2; ++j) {
      #pragma unroll
      for (int r = 0; r < 4; ++r) {
        int m = m0 + wr * 32 + i * 16 + lg * 4 + r;
        int n = n0 + wc * 32 + j * 16 + lr;
        float v = acc[i][j][r];
        if (bias) v += bias[n];
        size_t idx = (size_t)m * p.N + n;
        switch (p.op) {
          case 0: p.OH[p.Ooff[z] + idx] = f2bf(v); break;
          case 1: p.OH[p.Ooff[z] + idx] =
                    f2bf(0.5f * v * (1.f + erff(v * 0.70710678118654752f))); break;
          case 2: p.OH[p.Ooff[z] + idx] = f2bf(1.f / (1.f + __expf(-v))); break;
          case 3: p.OH[p.Ooff[z] + idx] =
                    f2bf(p.residF[p.roff[z] + idx] + v); break;
          case 4: {
            float gate = 1.f / (1.f + __expf(-v));
            p.OF[p.Ooff[z] + idx] = b2f(p.residH[p.roff[z] + idx]) +
                                    gate * b2f(p.extraH[p.eoff[z] + idx]);
          } break;
          case 5: {
            float gm = p.extraH ? b2f(p.extraH[p.eoff[z] + idx]) : 1.f;
            p.OH[p.Ooff[z] + idx] = f2bf(b2f(p.residH[p.roff[z] + idx]) + gm * v);
          } break;
        }
      }
    }
  }
}

// 6-part bridge: O = bf16( (sum_s y[bl_s] @ br_w[s]) / 6 + bbias )
__global__ __launch_bounds__(256) void bridge_kernel(const u16* __restrict__ yb,
                                                     const u16* __restrict__ wtBr,
                                                     const float* __restrict__ bbias,
                                                     u16* __restrict__ O) {
  __shared__ __align__(16) u16 As[64][40];
  __shared__ __align__(16) u16 Bs[64][40];
  const int m0 = blockIdx.x * 64, n0 = blockIdx.y * 64;
  const int tid = threadIdx.x;
  f32x4 acc[2][2] = {};
  const int bl[6] = {0, 1, 2, 4, 5, 6};
  for (int s = 0; s < 6; ++s)
    mfma_part_h(yb + (size_t)bl[s] * BANDE, wtBr + (size_t)s * 16384,
                128, m0, n0, tid, As, Bs, acc);

  const int lane = tid & 63;
  const int wv = tid >> 6;
  const int wr = wv >> 1, wc = wv & 1;
  const int lr = lane & 15, lg = lane >> 4;
  #pragma unroll
  for (int i = 0; i < 2; ++i)
    #pragma unroll
    for (int j = 0; j < 2; ++j)
      #pragma unroll
      for (int r = 0; r < 4; ++r) {
        int m = m0 + wr * 32 + i * 16 + lg * 4 + r;
        int n = n0 + wc * 32 + j * 16 + lr;
        O[(size_t)m * 128 + n] = f2bf(acc[i][j][r] * (1.f / 6.f) + bbias[n]);
      }
}

// ---------------------------------------------------------------------------
// MFMA flash attention, causal, bf16 (unchanged from round 9).
// ---------------------------------------------------------------------------
__global__ __launch_bounds__(256) void attn_kernel(const u16* __restrict__ q,
                                                   const u16* __restrict__ k,
                                                   const u16* __restrict__ v,
                                                   u16* __restrict__ o) {
  const int band = blockIdx.x >> 8;
  const int rest = blockIdx.x & 255;
  const int qt = rest & 7;
  const int bh = rest >> 3;
  const int h  = bh & 1;
  const int b  = bh >> 1;
  const size_t rowbase = ((size_t)band * BBATCH + b) * TSEQ;

  const int tid  = threadIdx.x;
  const int w    = tid >> 6;
  const int lane = tid & 63;
  const int lr   = lane & 15;
  const int lg   = lane >> 4;

  __shared__ __align__(16) u16 Qs[64][72];
  __shared__ __align__(16) u16 Ks[64][72];
  __shared__ __align__(16) u16 Vs[64][72];
  __shared__ __align__(16) u16 Ps[4][16][72];

  #pragma unroll
  for (int it = 0; it < 2; ++it) {
    int idx = tid + it * 256;
    int r = idx >> 3, c8 = (idx & 7) << 3;
    *(short8*)&Qs[r][c8] =
        *(const short8*)&q[(rowbase + qt * 64 + r) * DMODEL + h * 64 + c8];
  }

  f32x4 oacc[4] = {};
  float m[4], l[4];
  #pragma unroll
  for (int r = 0; r < 4; ++r) { m[r] = -1e30f; l[r] = 0.f; }

  for (int kt = 0; kt <= qt; ++kt) {
    __syncthreads();
    #pragma unroll
    for (int it = 0; it < 2; ++it) {
      int idx = tid + it * 256;
      int r = idx >> 3, c8 = (idx & 7) << 3;
      *(short8*)&Ks[r][c8] =
          *(const short8*)&k[(rowbase + kt * 64 + r) * DMODEL + h * 64 + c8];
    }
    #pragma unroll
    for (int it = 0; it < 2; ++it) {
      int idx = tid + it * 256;
      int kp = idx >> 4, d0 = (idx & 15) << 2;
      size_t g0 = (rowbase + kt * 64 + 2 * kp) * DMODEL + h * 64 + d0;
      u32 a0 = *(const u32*)&v[g0];
      u32 a1 = *(const u32*)&v[g0 + 2];
      u32 b0 = *(const u32*)&v[g0 + DMODEL];
      u32 b1 = *(const u32*)&v[g0 + DMODEL + 2];
      *(u32*)&Vs[d0 + 0][2 * kp] = (a0 & 0xFFFFu) | (b0 << 16);
      *(u32*)&Vs[d0 + 1][2 * kp] = (a0 >> 16) | (b0 & 0xFFFF0000u);
      *(u32*)&Vs[d0 + 2][2 * kp] = (a1 & 0xFFFFu) | (b1 << 16);
      *(u32*)&Vs[d0 + 3][2 * kp] = (a1 >> 16) | (b1 & 0xFFFF0000u);
    }
    __syncthreads();

    f32x4 s[4] = {};
    #pragma unroll
    for (int c = 0; c < 2; ++c) {
      short8 a = *(const short8*)&Qs[w * 16 + lr][c * 32 + lg * 8];
      #pragma unroll
      for (int j = 0; j < 4; ++j) {
        short8 bb = *(const short8*)&Ks[j * 16 + lr][c * 32 + lg * 8];
        s[j] = __builtin_amdgcn_mfma_f32_16x16x32_bf16(a, bb, s[j], 0, 0, 0);
      }
    }
    #pragma unroll
    for (int j = 0; j < 4; ++j)
      #pragma unroll
      for (int r = 0; r < 4; ++r)
        s[j][r] *= 0.125f;

    if (kt == qt) {
      #pragma unroll
      for (int j = 0; j < 4; ++j)
        #pragma unroll
        for (int r = 0; r < 4; ++r) {
          int row = w * 16 + lg * 4 + r;
          int col = j * 16 + lr;
          if (col > row) s[j][r] = -1e30f;
        }
    }

    float mx[4], al[4];
    #pragma unroll
    for (int r = 0; r < 4; ++r)
      mx[r] = fmaxf(fmaxf(s[0][r], s[1][r]), fmaxf(s[2][r], s[3][r]));
    #pragma unroll
    for (int off = 1; off <= 8; off <<= 1)
      #pragma unroll
      for (int r = 0; r < 4; ++r)
        mx[r] = fmaxf(mx[r], __shfl_xor(mx[r], off));
    #pragma unroll
    for (int r = 0; r < 4; ++r) {
      float mn = fmaxf(m[r], mx[r]);
      al[r] = __expf(m[r] - mn);
      m[r] = mn;
    }
    float rs[4] = {0.f, 0.f, 0.f, 0.f};
    #pragma unroll
    for (int j = 0; j < 4; ++j)
      #pragma unroll
      for (int r = 0; r < 4; ++r) {
        float pe = __expf(s[j][r] - m[r]);
        s[j][r] = pe;
        rs[r] += pe;
      }
    #pragma unroll
    for (int off = 1; off <= 8; off <<= 1)
      #pragma unroll
      for (int r = 0; r < 4; ++r)
        rs[r] += __shfl_xor(rs[r], off);
    #pragma unroll
    for (int r = 0; r < 4; ++r) l[r] = l[r] * al[r] + rs[r];

    #pragma unroll
    for (int j = 0; j < 4; ++j)
      #pragma unroll
      for (int r = 0; r < 4; ++r)
        oacc[j][r] *= al[r];

    #pragma unroll
    for (int j = 0; j < 4; ++j)
      #pragma unroll
      for (int r = 0; r < 4; ++r)
        Ps[w][lg * 4 + r][j * 16 + lr] = f2bf(s[j][r]);

    #pragma unroll
    for (int c = 0; c < 2; ++c) {
      short8 a = *(const short8*)&Ps[w][lr][c * 32 + lg * 8];
      #pragma unroll
      for (int j = 0; j < 4; ++j) {
        short8 bb = *(const short8*)&Vs[j * 16 + lr][c * 32 + lg * 8];
        oacc[j] = __builtin_amdgcn_mfma_f32_16x16x32_bf16(a, bb, oacc[j], 0, 0, 0);
      }
    }
  }

  float inv[4];
  #pragma unroll
  for (int r = 0; r < 4; ++r) inv[r] = 1.f / l[r];
  #pragma unroll
  for (int j = 0; j < 4; ++j)
    #pragma unroll
    for (int r = 0; r < 4; ++r) {
      size_t row = rowbase + qt * 64 + w * 16 + lg * 4 + r;
      o[row * DMODEL + h * 64 + j * 16 + lr] = f2bf(oacc[j][r] * inv[r]);
    }
}

// ---------------------------------------------------------------------------
struct LNA {
  const u16* x;
  u16* xn;
  const float* ls[7];
  const float* lb[7];
};

__global__ __launch_bounds__(256) void ln_kernel(LNA p) {
  const int tid = threadIdx.x;
  const int rr = tid >> 6, lane = tid & 63;
  const size_t row = (size_t)blockIdx.x * 4 + rr;
  u32 wv = *(const u32*)&p.x[row * DMODEL + 2 * lane];
  float a = b2f((u16)wv), b = b2f((u16)(wv >> 16));
  float s = a + b;
  #pragma unroll
  for (int off = 32; off; off >>= 1) s += __shfl_xor(s, off);
  float mean = s * (1.f / 128.f);
  float da = a - mean, db = b - mean;
  float vs = da * da + db * db;
  #pragma unroll
  for (int off = 32; off; off >>= 1) vs += __shfl_xor(vs, off);
  float rstd = rsqrtf(vs * (1.f / 128.f) + 1e-5f);
  int band = (int)(row >> 13);
  const float* ls = p.ls[band];
  const float* lb = p.lb[band];
  *(u32*)&p.xn[row * DMODEL + 2 * lane] =
      pack2(da * rstd * ls[2 * lane] + lb[2 * lane],
            db * rstd * ls[2 * lane + 1] + lb[2 * lane + 1]);
}

__global__ void bias6_kernel(const float* __restrict__ br_b, float* __restrict__ out) {
  int d = threadIdx.x;
  float s = 0.f;
  #pragma unroll
  for (int j = 0; j < 6; ++j) s += br_b[j * 128 + d];
  out[d] = s * (1.f / 6.f);
}

__global__ __launch_bounds__(256) void cvt_kernel(const float* __restrict__ in,
                                                  u16* __restrict__ out) {
  size_t i = ((size_t)blockIdx.x * 256 + threadIdx.x) * 8;
  float4 a = *(const float4*)&in[i];
  float4 b = *(const float4*)&in[i + 4];
  uint4 st = {pack2(a.x, a.y), pack2(a.z, a.w), pack2(b.x, b.y), pack2(b.z, b.w)};
  *(uint4*)&out[i] = st;
}

// ---------------------------------------------------------------------------
extern "C" void kernel_launch(void* const* d_in, const int* in_sizes, int n_in,
                              void* d_out, int out_size, void* d_ws, size_t ws_size,
                              hipStream_t stream) {
  bool dict = (in_sizes[2] != 896);
  const float* bands = (const float*)d_in[0];
  const float* Wq = (const float*)d_in[1];
  const float *Wk, *Wv, *Wo, *bq, *bk, *bv, *bo;
  if (dict) {
    Wk = (const float*)d_in[2]; Wv = (const float*)d_in[3]; Wo = (const float*)d_in[4];
    bq = (const float*)d_in[5]; bk = (const float*)d_in[6];
    bv = (const float*)d_in[7]; bo = (const float*)d_in[8];
  } else {
    bq = (const float*)d_in[2]; Wk = (const float*)d_in[3]; bk = (const float*)d_in[4];
    Wv = (const float*)d_in[5]; bv = (const float*)d_in[6];
    Wo = (const float*)d_in[7]; bo = (const float*)d_in[8];
  }
  const float* g_ls = (const float*)d_in[9];
  const float* g_lb = (const float*)d_in[10];
  const float* g_w1 = (const float*)d_in[11];
  const float* g_b1 = (const float*)d_in[12];
  const float* g_w2 = (const float*)d_in[13];
  const float* g_b2 = (const float*)d_in[14];
  const float* g_wg = (const float*)d_in[15];
  const float* g_bg = (const float*)d_in[16];
  const float* h_ls = (const float*)d_in[17];
  const float* h_lb = (const float*)d_in[18];
  const float* h_w1 = (const float*)d_in[19];
  const float* h_b1 = (const float*)d_in[20];
  const float* h_w2 = (const float*)d_in[21];
  const float* h_b2 = (const float*)d_in[22];
  const float* r_ls = (const float*)d_in[23];
  const float* r_lb = (const float*)d_in[24];
  const float* r_w1 = (const float*)d_in[25];
  const float* r_b1 = (const float*)d_in[26];
  const float* r_w2 = (const float*)d_in[27];
  const float* r_b2 = (const float*)d_in[28];
  const float* wp_w = (const float*)d_in[29];
  const float* wp_b = (const float*)d_in[30];
  const float* wg_w = (const float*)d_in[31];
  const float* wg_b = (const float*)d_in[32];
  const float* br_w = (const float*)d_in[33];
  const float* br_b = (const float*)d_in[34];
  const float* bg_w = (const float*)d_in[35];
  const float* bg_b = (const float*)d_in[36];
  float* out = (float*)d_out;

  const float* lsP[7] = {g_ls, g_ls + 128, g_ls + 256, h_ls, h_ls + 128, r_ls, r_ls + 128};
  const float* lbP[7] = {g_lb, g_lb + 128, g_lb + 256, h_lb, h_lb + 128, r_lb, r_lb + 128};
  const float* b1p[7] = {g_b1, g_b1 + 256, g_b1 + 512,
                         h_b1, h_b1 + 384, r_b1, r_b1 + 512};
  const float* b2p[7] = {g_b2, g_b2 + 128, g_b2 + 256,
                         h_b2, h_b2 + 128, r_b2, r_b2 + 128};

  auto LP = [&](PArgs& p, int Z) {
    dim3 grid(MBAND / 64, p.N / 64, Z);
    gemm_b<<<grid, dim3(256), 0, stream>>>(p);
  };

  // ---- workspace: round-9 bf16 activations + ~3 MB transposed-weight arena ----
  const size_t HIDSZ = (size_t)MBAND * 2304;
  u16* H = (u16*)d_ws;
  u16* hidh   = H;                       // HIDSZ (overlays bandsH, later info/bridge)
  u16* bandsH = hidh;                    // 7 BANDE, dead after QKV
  u16* qh = H + HIDSZ;
  u16* kh = qh + 7 * BANDE;
  u16* vh = kh + 7 * BANDE;
  u16* oh = vh + 7 * BANDE;
  u16* wt = oh + 7 * BANDE;              // transposed weights (bf16 [N][K])
  u16* wtQ   = wt;
  u16* wtK   = wtQ + 7 * 16384;
  u16* wtV   = wtK + 7 * 16384;
  u16* wtO   = wtV + 7 * 16384;
  u16* wtGwg = wtO + 7 * 16384;
  u16* wtWp  = wtGwg + 3 * 16384;
  u16* wtBr  = wtWp + 3 * 16384;
  u16* wtWg  = wtBr + 6 * 16384;         // 3 i x 2 K-parts
  u16* wtBg  = wtWg + 6 * 16384;         // 2 K-parts
  u16* wtG1  = wtBg + 2 * 16384;
  u16* wtH1  = wtG1 + 3 * 32768;
  u16* wtR1  = wtH1 + 2 * 49152;
  u16* wtG2  = wtR1 + 2 * 65536;
  u16* wtH2  = wtG2 + 3 * 32768;
  u16* wtR2  = wtH2 + 2 * 49152;
  float* bbias = (float*)(wtR2 + 2 * 65536);
  u16* xh = qh;
  u16* xnh = kh;
  u16* gateh = vh;
  u16* yh = oh;
  u16* infoh = hidh;
  u16* bridgeh = hidh + 6 * BANDE;

  // 0a. bands -> bf16
  cvt_kernel<<<dim3((unsigned)(7 * BANDE / (8 * 256))), dim3(256), 0, stream>>>(bands, bandsH);

  // 0b. transpose all weights once (fp32 [K][N] -> bf16 [N][K])
  {
    TArgs ta{};
    int ns = 0;
    auto add = [&](const float* s, u16* d, int K, int N) {
      ta.s[ns].src = s; ta.s[ns].dst = d; ta.s[ns].K = K; ta.s[ns].N = N; ++ns;
    };
    for (int z = 0; z < 7; ++z) add(Wq + z * 16384, wtQ + z * 16384, 128, 128);
    for (int z = 0; z < 7; ++z) add(Wk + z * 16384, wtK + z * 16384, 128, 128);
    for (int z = 0; z < 7; ++z) add(Wv + z * 16384, wtV + z * 16384, 128, 128);
    for (int z = 0; z < 7; ++z) add(Wo + z * 16384, wtO + z * 16384, 128, 128);
    for (int i = 0; i < 3; ++i) add(g_wg + i * 16384, wtGwg + i * 16384, 128, 128);
    for (int i = 0; i < 3; ++i) add(wp_w + i * 16384, wtWp + i * 16384, 128, 128);
    for (int j = 0; j < 6; ++j) add(br_w + j * 16384, wtBr + j * 16384, 128, 128);
    for (int i = 0; i < 3; ++i) {
      add(wg_w + i * 32768,         wtWg + (size_t)(2 * i) * 16384,     128, 128);
      add(wg_w + i * 32768 + 16384, wtWg + (size_t)(2 * i + 1) * 16384, 128, 128);
    }
    add(bg_w,         wtBg,         128, 128);
    add(bg_w + 16384, wtBg + 16384, 128, 128);
    for (int i = 0; i < 3; ++i) add(g_w1 + i * 32768, wtG1 + i * 32768, 128, 256);
    for (int i = 0; i < 2; ++i) add(h_w1 + i * 49152, wtH1 + i * 49152, 128, 384);
    for (int i = 0; i < 2; ++i) add(r_w1 + i * 65536, wtR1 + i * 65536, 128, 512);
    for (int i = 0; i < 3; ++i) add(g_w2 + i * 32768, wtG2 + i * 32768, 256, 128);
    for (int i = 0; i < 2; ++i) add(h_w2 + i * 49152, wtH2 + i * 49152, 384, 128);
    for (int i = 0; i < 2; ++i) add(r_w2 + i * 65536, wtR2 + i * 65536, 512, 128);
    wtrans_kernel<<<dim3(64, 1, 62), dim3(256), 0, stream>>>(ta);
  }

  // 1-3. Q/K/V projections, Z=7 each
  const u16* wtQKV[3] = {wtQ, wtK, wtV};
  const float* bqkv[3] = {bq, bk, bv};
  u16* oqkv[3] = {qh, kh, vh};
  for (int w = 0; w < 3; ++w) {
    PArgs p{};
    p.A = bandsH; p.WT = wtQKV[w]; p.bias = bqkv[w]; p.OH = oqkv[w];
    for (int z = 0; z < 7; ++z) {
      p.Aoff[z] = z * BANDE; p.Woff[z] = (size_t)z * 16384;
      p.boff[z] = (size_t)z * 128; p.Ooff[z] = z * BANDE;
    }
    p.K = 128; p.N = 128; p.op = 0;
    LP(p, 7);
  }

  // 4. attention
  attn_kernel<<<dim3(NBAND * 256), dim3(256), 0, stream>>>(qh, kh, vh, oh);

  // 5. x = bands + o @ Wo + bo   (resid fp32 input, out bf16)
  {
    PArgs p{};
    p.A = oh; p.WT = wtO; p.bias = bo; p.residF = bands; p.OH = xh;
    for (int z = 0; z < 7; ++z) {
      p.Aoff[z] = z * BANDE; p.Woff[z] = (size_t)z * 16384;
      p.boff[z] = (size_t)z * 128; p.roff[z] = z * BANDE; p.Ooff[z] = z * BANDE;
    }
    p.K = 128; p.N = 128; p.op = 3;
    LP(p, 7);
  }

  // 6. LN
  {
    LNA p{};
    p.x = xh; p.xn = xnh;
    for (int n = 0; n < 7; ++n) { p.ls[n] = lsP[n]; p.lb[n] = lbP[n]; }
    ln_kernel<<<dim3(NBAND * MBAND / 4), dim3(256), 0, stream>>>(p);
  }

  // 7. geo gates, Z=3
  {
    PArgs p{};
    p.A = xh; p.WT = wtGwg; p.bias = g_bg; p.OH = gateh;
    for (int z = 0; z < 3; ++z) {
      p.Aoff[z] = z * BANDE; p.Woff[z] = (size_t)z * 16384;
      p.boff[z] = (size_t)z * 128; p.Ooff[z] = z * BANDE;
    }
    p.K = 128; p.N = 128; p.op = 2;
    LP(p, 3);
  }

  // 8-13. MLP per group: geo(3,256) hyb(2,384) rea(2,512)
  const int gcnt[3] = {3, 2, 2};
  const int gbase[3] = {0, 3, 5};
  const int gN1[3] = {256, 384, 512};
  u16* wtW1[3] = {wtG1, wtH1, wtR1};
  u16* wtW2[3] = {wtG2, wtH2, wtR2};
  for (int grp = 0; grp < 3; ++grp) {
    int cnt = gcnt[grp], base = gbase[grp], N1 = gN1[grp];
    size_t hstride = (size_t)MBAND * N1;
    size_t wsz = (size_t)128 * N1;
    {  // hidden = gelu(xn @ w1 + b1)
      PArgs p{};
      p.A = xnh; p.WT = wtW1[grp]; p.bias = b1p[base]; p.OH = hidh;
      for (int z = 0; z < cnt; ++z) {
        p.Aoff[z] = (size_t)(base + z) * BANDE;
        p.Woff[z] = z * wsz;
        p.boff[z] = (size_t)(b1p[base + z] - b1p[base]);
        p.Ooff[z] = z * hstride;
      }
      p.K = 128; p.N = N1; p.op = 1;
      LP(p, cnt);
    }
    {  // y = x + [gate]*(hid @ w2 + b2)
      PArgs p{};
      p.A = hidh; p.WT = wtW2[grp]; p.bias = b2p[base];
      p.residH = xh; p.OH = yh;
      if (grp == 0) p.extraH = gateh;
      for (int z = 0; z < cnt; ++z) {
        p.Aoff[z] = z * hstride;
        p.Woff[z] = z * wsz;
        p.boff[z] = (size_t)(b2p[base + z] - b2p[base]);
        p.roff[z] = (size_t)(base + z) * BANDE;
        p.eoff[z] = z * BANDE;
        p.Ooff[z] = (size_t)(base + z) * BANDE;
      }
      p.K = N1; p.N = 128; p.op = 5;
      LP(p, cnt);
    }
  }

  // 14. info, Z=6
  {
    PArgs p{};
    p.A = yh; p.WT = wtWp; p.bias = wp_b; p.OH = infoh;
    for (int z = 0; z < 6; ++z) {
      int t = (z < 3) ? z : z + 1;
      int src = 6 - t;
      int i = (t < 3) ? t : 6 - t;
      p.Aoff[z] = (size_t)src * BANDE; p.Woff[z] = (size_t)i * 16384;
      p.boff[z] = (size_t)i * 128; p.Ooff[z] = (size_t)z * BANDE;
    }
    p.K = 128; p.N = 128; p.op = 0;
    LP(p, 6);
  }

  // 15. final gates (2-part K), fp32 out
  {
    PArgs p{};
    p.A = yh; p.WT = wtWg; p.A2 = infoh; p.WT2 = wtWg;
    p.bias = wg_b; p.residH = yh; p.extraH = infoh; p.OF = out;
    for (int z = 0; z < 6; ++z) {
      int t = (z < 3) ? z : z + 1;
      int i = (t < 3) ? t : 6 - t;
      p.Aoff[z] = (size_t)t * BANDE;  p.Woff[z] = (size_t)(2 * i) * 16384;
      p.A2off[z] = (size_t)z * BANDE; p.W2off[z] = (size_t)(2 * i + 1) * 16384;
      p.boff[z] = (size_t)i * 128;
      p.roff[z] = (size_t)t * BANDE;  p.eoff[z] = (size_t)z * BANDE;
      p.Ooff[z] = (size_t)t * BANDE;
    }
    p.K = 128; p.N = 128; p.op = 4;
    LP(p, 6);
  }

  // 16-17. bridge
  bias6_kernel<<<dim3(1), dim3(128), 0, stream>>>(br_b, bbias);
  bridge_kernel<<<dim3(MBAND / 64, 2), dim3(256), 0, stream>>>(yh, wtBr, bbias, bridgeh);

  // 18. band-3 final (2-part), fp32 out
  {
    PArgs p{};
    p.A = yh; p.WT = wtBg; p.A2 = bridgeh; p.WT2 = wtBg;
    p.bias = bg_b; p.residH = yh; p.extraH = bridgeh; p.OF = out;
    p.Aoff[0] = 3 * BANDE; p.Woff[0] = 0;
    p.A2off[0] = 0; p.W2off[0] = 16384;
    p.boff[0] = 0; p.roff[0] = 3 * BANDE; p.eoff[0] = 0; p.Ooff[0] = 3 * BANDE;
    p.K = 128; p.N = 128; p.op = 4;
    LP(p, 1);
  }
}